// Round 8
// baseline (388.867 us; speedup 1.0000x reference)
//
#include <hip/hip_runtime.h>
#include <stdint.h>

// Word2MatEncoder: out[b] = prod_{s=0..63} table[sent[b,s]]  (28x28 fp32 chain)
//
// R8: R5 skeleton (proven: 7 lanes x 4 rows/task, 9 tasks/wave, P=4 segments,
// global_load_lds staging, flat macro body, named-array ping-pong) with the
// per-step stall attacked:
//  - MATMUL explicitly double-buffers B-row reads (m0/m1 float4[7]): row k+1's
//    ds_read_b128s issue before row k's FMAs -> >=7 reads in flight instead of
//    whatever a 144-reg allocation allowed (R5 was LDS-latency exposed: waves
//    ~34% issue-busy).
//  - block = 1 wave -> __syncthreads replaced by precise waitcnts:
//    vmcnt(0) at step top (DMA of M_s landed), lgkmcnt(0) after MATMUL
//    (all ds_reads consumed) before overwriting LDS with M_{s+1}'s DMA.
// fp32 throughout (no fp32 MFMA on CDNA4; bf16 error compounds over 63 muls).

#define D 28
#define EMB 784
#define SEQ 64
#define NITEMS 2048
#define LPI 7            // lanes per task
#define IPW 9            // tasks per wave (63 of 64 lanes active)
#define RPL 4            // rows of the running product per lane
#define NCHUNK 28        // DMA chunks per matrix-set (1 row x 9 slots each)
#define CHUNK_F 256      // floats per chunk (64 lanes x 16B)
#define BUF_F (NCHUNK * CHUNK_F)  // 7168 floats = 28672 B

// s_waitcnt immediates (gfx9 encoding): vmcnt[3:0]=bits[3:0], vmcnt[5:4]=
// bits[15:14], exp=bits[6:4], lgkm=bits[11:8]. 0x0F70 = vmcnt(0) only;
// 0xC07F = lgkmcnt(0) only.
#define WAIT_VMCNT0 0x0F70
#define WAIT_LGKM0 0xC07F

typedef __attribute__((address_space(3))) uint32_t lds_u32;
typedef const __attribute__((address_space(1))) uint32_t glb_u32;

// Stage one matrix per slot into LDS. glane = matrix base + rl*16B (per lane);
// chunk t pulls row t (bytes [t*112, t*112+16) per lane) of each slot's matrix.
// Lane l writes its 16B at lds0 + t*1024 + l*16 (HW rule): slot s's row t
// floats sit at t*256 + s*28.
__device__ __forceinline__ void dma_mat(const float* glane, float* lds0) {
#pragma unroll
  for (int t = 0; t < NCHUNK; ++t)
    __builtin_amdgcn_global_load_lds((glb_u32*)(glane + t * D),
                                     (lds_u32*)(lds0 + t * CHUNK_F), 16, 0, 0);
}

// Cc = Aa @ M, M staged in LDS at Bs (row k at Bs + k*CHUNK_F, 28 floats).
// Software-pipelined: row k+1's 7 ds_read_b128 issue before row k's FMAs.
#define MATMUL(Aa, Cc)                                                         \
  do {                                                                         \
    float4 m0[7], m1[7];                                                       \
    _Pragma("unroll") for (int jv = 0; jv < 7; ++jv)                           \
        m0[jv] = *(const float4*)(Bs + 4 * jv);                                \
    _Pragma("unroll") for (int k = 0; k < D; k += 2) {                         \
      _Pragma("unroll") for (int jv = 0; jv < 7; ++jv)                         \
          m1[jv] = *(const float4*)(Bs + (k + 1) * CHUNK_F + 4 * jv);          \
      _Pragma("unroll") for (int jv = 0; jv < 7; ++jv) {                       \
        _Pragma("unroll") for (int r = 0; r < RPL; ++r) {                      \
          float a = Aa[r][k];                                                  \
          if (k == 0) {                                                        \
            Cc[r][4 * jv + 0] = a * m0[jv].x;                                  \
            Cc[r][4 * jv + 1] = a * m0[jv].y;                                  \
            Cc[r][4 * jv + 2] = a * m0[jv].z;                                  \
            Cc[r][4 * jv + 3] = a * m0[jv].w;                                  \
          } else {                                                             \
            Cc[r][4 * jv + 0] = fmaf(a, m0[jv].x, Cc[r][4 * jv + 0]);          \
            Cc[r][4 * jv + 1] = fmaf(a, m0[jv].y, Cc[r][4 * jv + 1]);          \
            Cc[r][4 * jv + 2] = fmaf(a, m0[jv].z, Cc[r][4 * jv + 2]);          \
            Cc[r][4 * jv + 3] = fmaf(a, m0[jv].w, Cc[r][4 * jv + 3]);          \
          }                                                                    \
        }                                                                      \
      }                                                                        \
      if (k + 2 < D) {                                                         \
        _Pragma("unroll") for (int jv = 0; jv < 7; ++jv)                       \
            m0[jv] = *(const float4*)(Bs + (k + 2) * CHUNK_F + 4 * jv);        \
      }                                                                        \
      _Pragma("unroll") for (int jv = 0; jv < 7; ++jv) {                       \
        _Pragma("unroll") for (int r = 0; r < RPL; ++r) {                      \
          float a = Aa[r][k + 1];                                              \
          Cc[r][4 * jv + 0] = fmaf(a, m1[jv].x, Cc[r][4 * jv + 0]);            \
          Cc[r][4 * jv + 1] = fmaf(a, m1[jv].y, Cc[r][4 * jv + 1]);            \
          Cc[r][4 * jv + 2] = fmaf(a, m1[jv].z, Cc[r][4 * jv + 2]);            \
          Cc[r][4 * jv + 3] = fmaf(a, m1[jv].w, Cc[r][4 * jv + 3]);            \
        }                                                                      \
      }                                                                        \
    }                                                                          \
  } while (0)

// One chain step: wait staged matrix, multiply, drain LDS reads, DMA next.
// Single-wave block: program order + waitcnts give all needed ordering.
#define STEP(Aa, Cc)                                                           \
  do {                                                                         \
    __builtin_amdgcn_s_waitcnt(WAIT_VMCNT0); /* M_s landed in LDS */           \
    MATMUL(Aa, Cc);                                                            \
    __builtin_amdgcn_s_waitcnt(WAIT_LGKM0); /* all ds_reads consumed */        \
    if (s + 1 < SEG_LEN) {                                                     \
      dma_mat(gn, lds);                                                        \
      int nn = (s + 2 < SEG_LEN) ? s + 2 : SEG_LEN - 1;                        \
      gn = glane(nn);                                                          \
    }                                                                          \
    ++s;                                                                       \
  } while (0)

// Product of SEG_LEN consecutive matrices (SEG_LEN-1 odd -> result in A1).
// GATHER: matrices are table[sp[s]]; else dense at src + (task*SEG_LEN+s)*EMB.
template <int SEG_LEN, int PSEG, bool GATHER>
__global__ __launch_bounds__(64, 1) void chain_kernel(
    const float* __restrict__ src, const int* __restrict__ sent,
    float* __restrict__ dst, int ntask) {
  __shared__ __align__(16) float lds[BUF_F];

  const int lane = threadIdx.x;
  int slot = lane / LPI;
  int rl = lane - slot * LPI;
  if (slot >= IPW) { slot = IPW - 1; rl = LPI - 1; }  // lane 63 mirrors lane 62
  int task = blockIdx.x * IPW + slot;
  if (task >= ntask) task = ntask - 1;  // tail duplicates (same values, benign)

  const int* sp = nullptr;
  if (GATHER) {
    const int item = task / PSEG;
    const int seg = task - item * PSEG;
    sp = sent + item * SEQ + seg * SEG_LEN;
  }
  auto glane = [&](int s) -> const float* {
    const float* m = GATHER ? src + (size_t)sp[s] * EMB
                            : src + ((size_t)task * SEG_LEN + s) * EMB;
    return m + rl * 4;  // this lane's 16B slice of each row
  };

  float A0[RPL][D], A1[RPL][D];

  // A0 = this lane's rows (rl*4 .. rl*4+3) of the first matrix (direct loads)
  {
    const float* m0 = GATHER ? src + (size_t)sp[0] * EMB
                             : src + (size_t)task * SEG_LEN * EMB;
#pragma unroll
    for (int r = 0; r < RPL; ++r) {
      const float* rp = m0 + (rl * RPL + r) * D;
#pragma unroll
      for (int jv = 0; jv < 7; ++jv) {
        float4 v = *(const float4*)(rp + 4 * jv);
        A0[r][4 * jv + 0] = v.x;
        A0[r][4 * jv + 1] = v.y;
        A0[r][4 * jv + 2] = v.z;
        A0[r][4 * jv + 3] = v.w;
      }
    }
  }

  // stage matrix 1; prefetch pointer for matrix 2
  dma_mat(glane(1), lds);
  const float* gn = glane(SEG_LEN > 2 ? 2 : 1);
  const float* Bs = lds + slot * (LPI * 4);  // slot*28 floats

  int s = 1;
#pragma unroll 1
  for (int p = 0; p < (SEG_LEN - 1) / 2; ++p) {
    STEP(A0, A1);
    STEP(A1, A0);
  }
  STEP(A0, A1);  // final step (SEG_LEN-1 is odd) -> result in A1

  // store
  {
    float* op = dst + (size_t)task * EMB;
#pragma unroll
    for (int r = 0; r < RPL; ++r) {
      float* rp = op + (rl * RPL + r) * D;
#pragma unroll
      for (int jv = 0; jv < 7; ++jv) {
        *(float4*)(rp + 4 * jv) =
            make_float4(A1[r][4 * jv + 0], A1[r][4 * jv + 1],
                        A1[r][4 * jv + 2], A1[r][4 * jv + 3]);
      }
    }
  }
}

extern "C" void kernel_launch(void* const* d_in, const int* in_sizes, int n_in,
                              void* d_out, int out_size, void* d_ws, size_t ws_size,
                              hipStream_t stream) {
  const float* table = (const float*)d_in[0];
  const int* sent = (const int*)d_in[1];
  float* out = (float*)d_out;

  const size_t need4 = (size_t)NITEMS * 4 * EMB * sizeof(float);  // 25.7 MB
  if (ws_size >= need4) {
    float* p = (float*)d_ws;
    // phase 1: 4 segments of 16 per item -> 8192 partials (contiguous per item)
    const int ntask1 = NITEMS * 4;
    chain_kernel<16, 4, true><<<(ntask1 + IPW - 1) / IPW, 64, 0, stream>>>(
        table, sent, p, ntask1);
    // phase 2: chain each item's 4 partials -> d_out
    chain_kernel<4, 1, false><<<(NITEMS + IPW - 1) / IPW, 64, 0, stream>>>(
        p, nullptr, out, NITEMS);
  } else {
    // fallback: direct 64-long chain per item straight into d_out
    chain_kernel<64, 1, true><<<(NITEMS + IPW - 1) / IPW, 64, 0, stream>>>(
        table, sent, out, NITEMS);
  }
}